// Round 10
// baseline (350.042 us; speedup 1.0000x reference)
//
#include <hip/hip_runtime.h>
#include <math.h>

// Problem constants (match reference)
#define NB   64     // num_groups (B)
#define NG   32     // group_size (G)
#define ND   2000   // output dim D
#define NM   16     // m_samples
#define NE   16     // noise dim
#define NDIN 256
#define NK   272    // DIN + E

__device__ __forceinline__ float clampf(float v, float lo, float hi) {
    return fminf(fmaxf(v, lo), hi);
}

__device__ __forceinline__ float softplusf(float v) {
    return (v > 20.f) ? v : log1pf(expf(v));
}

// Broadcast lane `lane`'s value wave-uniformly (lives in SGPR).
__device__ __forceinline__ float readlane_f(float v, int lane) {
    return __int_as_float(__builtin_amdgcn_readlane(__float_as_int(v), lane));
}

// Fully-packed butterfly: reduce v[0..31] across 64 lanes in 32 shuffles.
// Returns the wave total for g = (lane>>1)&31 (dup on lane pairs).
__device__ __forceinline__ float wave_sum32(float v[NG], int lane) {
    {   const bool hi = (lane & 32) != 0;
        #pragma unroll
        for (int k = 0; k < 16; ++k) {
            float s = hi ? v[k] : v[k + 16];
            float r = __shfl_xor(s, 32);
            v[k] = (hi ? v[k + 16] : v[k]) + r;
        }
    }
    {   const bool hi = (lane & 16) != 0;
        #pragma unroll
        for (int k = 0; k < 8; ++k) {
            float s = hi ? v[k] : v[k + 8];
            float r = __shfl_xor(s, 16);
            v[k] = (hi ? v[k + 8] : v[k]) + r;
        }
    }
    {   const bool hi = (lane & 8) != 0;
        #pragma unroll
        for (int k = 0; k < 4; ++k) {
            float s = hi ? v[k] : v[k + 4];
            float r = __shfl_xor(s, 8);
            v[k] = (hi ? v[k + 4] : v[k]) + r;
        }
    }
    {   const bool hi = (lane & 4) != 0;
        #pragma unroll
        for (int k = 0; k < 2; ++k) {
            float s = hi ? v[k] : v[k + 2];
            float r = __shfl_xor(s, 4);
            v[k] = (hi ? v[k + 2] : v[k]) + r;
        }
    }
    {   const bool hi = (lane & 2) != 0;
        float s = hi ? v[0] : v[1];
        float r = __shfl_xor(s, 2);
        v[0] = (hi ? v[1] : v[0]) + r;
    }
    v[0] += __shfl_xor(v[0], 1);
    return v[0];
}

// ---------------------------------------------------------------------------
// Mega kernel: grid 832 x 512 threads, __launch_bounds__(512, 1).
//   blocks 0..255  : xpred (8 rows x 2000 d each) -> xp, then signal cnt[b]
//   blocks 256..319: IPF (one-time wait on cnt[b]==4) + integerization
//   blocks 320..831: loss partials (8 d-chunks x 64 b)
// Handoff is ONE-TIME per IPF block (round-3 lesson: per-iteration cross-WG
// sync is catastrophic; a single producer->consumer wait is ~20 us total).
// Deadlock-free: loss blocks have no dependencies and always retire, so
// xpred blocks always eventually get resident slots, whatever the dispatch
// order.  xpred placed first in blockIdx order so it typically runs first.
// ---------------------------------------------------------------------------

// ---- xpred path: identical arithmetic to the old k3 (xp bit-stable) ----
__device__ __forceinline__ void xpred_path(
        const float* __restrict__ x, const float* __restrict__ nsamp,
        const float* __restrict__ W, const float* __restrict__ bias,
        float* __restrict__ xp, int* __restrict__ cnt,
        float* smem, int rb, int t) {
    float* xr = smem;                    // [8][272]
    #pragma unroll
    for (int r = 0; r < 8; ++r) {
        const int row = rb * 8 + r;
        if (t < 256)      xr[r * NK + t] = x[(size_t)row * NDIN + t];
        else if (t < NK)  xr[r * NK + t] = nsamp[row * NE + (t - 256)];
    }
    __syncthreads();
    const int d = 4 * t;
    if (d < ND) {                        // t < 500; no early return (barrier below)
        float acc[8][4];
        #pragma unroll
        for (int r = 0; r < 8; ++r) {
            acc[r][0] = 0.f; acc[r][1] = 0.f; acc[r][2] = 0.f; acc[r][3] = 0.f;
        }
        for (int k = 0; k < NK; k += 4) {
            float4 w[4];
            #pragma unroll
            for (int kk = 0; kk < 4; ++kk)
                w[kk] = *(const float4*)&W[(size_t)(k + kk) * ND + d];
            #pragma unroll
            for (int r = 0; r < 8; ++r) {
                const float4 xv = *(const float4*)&xr[r * NK + k];
                acc[r][0] += xv.x * w[0].x + xv.y * w[1].x + xv.z * w[2].x + xv.w * w[3].x;
                acc[r][1] += xv.x * w[0].y + xv.y * w[1].y + xv.z * w[2].y + xv.w * w[3].y;
                acc[r][2] += xv.x * w[0].z + xv.y * w[1].z + xv.z * w[2].z + xv.w * w[3].z;
                acc[r][3] += xv.x * w[0].w + xv.y * w[1].w + xv.z * w[2].w + xv.w * w[3].w;
            }
        }
        const float4 bv = *(const float4*)&bias[d];
        #pragma unroll
        for (int r = 0; r < 8; ++r) {
            float4 o;
            o.x = softplusf(acc[r][0] + bv.x);
            o.y = softplusf(acc[r][1] + bv.y);
            o.z = softplusf(acc[r][2] + bv.z);
            o.w = softplusf(acc[r][3] + bv.w);
            *(float4*)&xp[(size_t)(rb * 8 + r) * ND + d] = o;
        }
    }
    // publish: all stores done -> fence -> count.  4 xpred blocks per b.
    __syncthreads();
    __threadfence();
    if (t == 0) atomicAdd(&cnt[rb >> 2], 1);
}

// ---- IPF path: thread owns d = 4t..4t+3 full-column (all 32 g) ----
__device__ __forceinline__ void ipf_path(
        const float* __restrict__ xp, const int* __restrict__ tsum,
        float* __restrict__ out, const int* __restrict__ cnt,
        float* smem, int b, int t) {
    const int lane = t & 63, w = t >> 6;      // wave 0..7
    const int d0 = t * 4;
    const bool valid = (d0 < ND);             // t < 500
    const int g_own = (lane >> 1) & 31;

    float* wred = smem;                       // [2][8][32] floats, dbuf

    // ONE-TIME wait for this b's 4 xpred blocks (acquire orders later loads)
    {
        const int* cb = &cnt[b];
        while (__hip_atomic_load(cb, __ATOMIC_ACQUIRE,
                                 __HIP_MEMORY_SCOPE_AGENT) < 4)
            __builtin_amdgcn_s_sleep(16);
    }

    // load y0 = max(x_pred, 0)
    float y0r[4][NG];
    #pragma unroll
    for (int g = 0; g < NG; ++g) {
        float4 v = make_float4(0.f, 0.f, 0.f, 0.f);
        if (valid) v = *(const float4*)(xp + (size_t)(b * NG + g) * ND + d0);
        y0r[0][g] = fmaxf(v.x, 0.f);
        y0r[1][g] = fmaxf(v.y, 0.f);
        y0r[2][g] = fmaxf(v.z, 0.f);
        y0r[3][g] = fmaxf(v.w, 0.f);
    }
    float Cc[4] = {0.f, 0.f, 0.f, 0.f};
    if (valid) {
        const int4 ci = *(const int4*)(tsum + (size_t)b * ND + d0);
        Cc[0] = (float)ci.x; Cc[1] = (float)ci.y; Cc[2] = (float)ci.z; Cc[3] = (float)ci.w;
    }
    float Ac[4] = {1.f, 1.f, 1.f, 1.f};
    float Bown = 1.f;                         // lane-pair's B[g_own]
    float Rown;                               // lane-pair's R[g_own]

    // prologue: row anchors R (buf 0)
    {
        float v[NG];
        #pragma unroll
        for (int g = 0; g < NG; ++g)
            v[g] = y0r[0][g] + y0r[1][g] + y0r[2][g] + y0r[3][g];
        const float tot = wave_sum32(v, lane);
        if ((lane & 1) == 0) wred[w * NG + g_own] = tot;
        __syncthreads();
        float s = 0.f;
        #pragma unroll
        for (int w2 = 0; w2 < 8; ++w2) s += wred[w2 * NG + g_own];
        Rown = s;
    }

    // 60 IPF iterations, ONE barrier each (double-buffered wred)
    for (int q = 1; q <= 60; ++q) {
        // column phase (thread-local; B broadcast via readlane -> SGPRs)
        float s0 = 0.f, s1 = 0.f, s2 = 0.f, s3 = 0.f;
        #pragma unroll
        for (int g = 0; g < NG; ++g) {
            const float bg = readlane_f(Bown, 2 * g);
            s0 += y0r[0][g] * bg; s1 += y0r[1][g] * bg;
            s2 += y0r[2][g] * bg; s3 += y0r[3][g] * bg;
        }
        Ac[0] *= clampf(Cc[0] / fmaxf(Ac[0] * s0, 1e-12f), 0.75f, 1.25f);
        Ac[1] *= clampf(Cc[1] / fmaxf(Ac[1] * s1, 1e-12f), 0.75f, 1.25f);
        Ac[2] *= clampf(Cc[2] / fmaxf(Ac[2] * s2, 1e-12f), 0.75f, 1.25f);
        Ac[3] *= clampf(Cc[3] / fmaxf(Ac[3] * s3, 1e-12f), 0.75f, 1.25f);
        // row phase
        float v[NG];
        #pragma unroll
        for (int g = 0; g < NG; ++g)
            v[g] = y0r[0][g] * Ac[0] + y0r[1][g] * Ac[1]
                 + y0r[2][g] * Ac[2] + y0r[3][g] * Ac[3];
        const float tot = wave_sum32(v, lane);
        const int buf = (q & 1) * (8 * NG);
        if ((lane & 1) == 0) wred[buf + w * NG + g_own] = tot;
        __syncthreads();
        float s = 0.f;
        #pragma unroll
        for (int w2 = 0; w2 < 8; ++w2) s += wred[buf + w2 * NG + g_own];
        Bown *= clampf(Rown / fmaxf(Bown * s, 1e-12f), 0.75f, 1.25f);
    }

    // epilogue: final scale + exact integerization, thread-local per d.
    // Rank-based neg branch (reference-equivalent): no dynamic indexing.
    if (!valid) return;

    unsigned pk[NG];
    #pragma unroll
    for (int g = 0; g < NG; ++g) pk[g] = 0u;

    #pragma unroll
    for (int j = 0; j < 4; ++j) {
        float fr[NG];
        int   yv[NG];
        float s = 0.f;
        #pragma unroll
        for (int g = 0; g < NG; ++g) {
            const float z = y0r[j][g] * Ac[j] * readlane_f(Bown, 2 * g);
            fr[g] = z;
            s += z;
        }
        const float F = Cc[j] / fmaxf(s, 1e-12f);
        int isum = 0;
        #pragma unroll
        for (int g = 0; g < NG; ++g) {
            const float y = fr[g] * F;
            const float fl = floorf(y);
            yv[g] = (int)fl;
            fr[g] = y - fl;
            isum += yv[g];
        }
        const int Ci = (int)Cc[j];
        const int need = Ci - isum;
        const int pos = max(need, 0);
        const int q = pos >> 5;
        const int r = pos & 31;
        #pragma unroll
        for (int g = 0; g < NG; ++g) yv[g] += q;
        #pragma unroll
        for (int g = 0; g < NG; ++g) {       // stable DESCENDING rank on frac
            int rank = 0;
            #pragma unroll
            for (int h = 0; h < NG; ++h) {
                if (h == g) continue;
                rank += (h < g) ? (fr[h] >= fr[g] ? 1 : 0) : (fr[h] > fr[g] ? 1 : 0);
            }
            if (rank < r) yv[g] += 1;
        }
        // negative residual: one-shot ascending rank among yv>0 (== reference)
        int neg = max(-need, 0);
        neg = min(neg, isum);
        if (__builtin_expect(neg > 0, 0)) {
            const int q2 = neg >> 5;
            int removed = 0;
            #pragma unroll
            for (int g = 0; g < NG; ++g) {
                const int yb = yv[g];
                const int yn = max(yb - q2, 0);
                removed += yb - yn;
                yv[g] = yn;
            }
            const int r2 = neg - removed;
            if (r2 > 0) {
                const float INF = __builtin_inff();
                #pragma unroll
                for (int g = 0; g < NG; ++g) {
                    const float fg = (yv[g] > 0) ? fr[g] : INF;
                    int rank = 0;
                    #pragma unroll
                    for (int h = 0; h < NG; ++h) {
                        if (h == g) continue;
                        const float fh = (yv[h] > 0) ? fr[h] : INF;
                        rank += (h < g) ? (fh <= fg ? 1 : 0) : (fh < fg ? 1 : 0);
                    }
                    if (rank < r2) yv[g] = max(yv[g] - 1, 0);
                }
            }
        }
        #pragma unroll
        for (int g = 0; g < NG; ++g)
            pk[g] |= ((unsigned)yv[g]) << (8 * j);   // yv <= C <= 199 < 256
    }
    #pragma unroll
    for (int g = 0; g < NG; ++g) {
        float* op = &out[1 + (size_t)(b * NG + g) * ND + d0];
        op[0] = (float)(pk[g] & 0xffu);
        op[1] = (float)((pk[g] >> 8) & 0xffu);
        op[2] = (float)((pk[g] >> 16) & 0xffu);
        op[3] = (float)((pk[g] >> 24) & 0xffu);
    }
}

// ---- loss-partials path: 512 blocks = 8 d-chunks x 64 b (unchanged) ----
__device__ __forceinline__ void loss_path(
        const float* __restrict__ x, const float* __restrict__ nl,
        const float* __restrict__ tgt, const float* __restrict__ W,
        const float* __restrict__ bias, float* __restrict__ res2,
        float* smem, int cx, int b, int t) {
    float* xsl = smem;                 // 256
    float* nsl = smem + 256;           // 256
    float* tgl = smem + 512;           // 252
    float* pt  = smem + 764;           // 16 x 252

    if (t < 256) {
        const float* xb = x + (size_t)b * NG * NDIN;
        float s = 0.f;
        for (int g = 0; g < NG; ++g) s += xb[g * NDIN + t];
        xsl[t] = s;
        const float* nb = nl + (size_t)b * NG * (NM * NE);
        float s2 = 0.f;
        for (int g = 0; g < NG; ++g) s2 += nb[g * (NM * NE) + t];
        nsl[t] = s2;
    }

    int tm = 0, tn = 0;
    if (t >= 16 && t < 152) {
        int p = t - 16;
        for (int m = 0; m < NM; ++m) {
            int c = NM - m;
            if (p < c) { tm = m; tn = m + p; break; }
            p -= c;
        }
    }
    __syncthreads();

    const int d = cx * 250 + t;
    if (t < 250) {
        tgl[t] = tgt[b * ND + d];
        float xw = 0.f;
        #pragma unroll 8
        for (int k = 0; k < NDIN; ++k) xw += xsl[k] * W[(size_t)k * ND + d];
        float we[NE];
        #pragma unroll
        for (int e = 0; e < NE; ++e) we[e] = W[(size_t)(NDIN + e) * ND + d];
        const float base0 = xw + (float)NG * bias[d];
        #pragma unroll
        for (int m = 0; m < NM; ++m) {
            float pm = base0;
            #pragma unroll
            for (int e = 0; e < NE; ++e) pm += nsl[m * NE + e] * we[e];
            pt[m * 252 + t] = pm;
        }
    }
    if (t < 32) {                      // zero-pad cols 250,251
        pt[(t >> 1) * 252 + 250 + (t & 1)] = 0.f;
        if (t < 2) tgl[250 + t] = 0.f;
    }
    __syncthreads();

    float acc = 0.f;
    if (t < 16) {
        const float4* pa  = (const float4*)&pt[t * 252];
        const float4* tga = (const float4*)&tgl[0];
        for (int i = 0; i < 63; ++i) {
            float4 pv = pa[i], tv = tga[i];
            float e0 = pv.x - tv.x, e1 = pv.y - tv.y, e2 = pv.z - tv.z, e3 = pv.w - tv.w;
            acc += e0 * e0 + e1 * e1 + e2 * e2 + e3 * e3;
        }
    } else if (t < 152) {
        const float4* pa = (const float4*)&pt[tm * 252];
        const float4* pb = (const float4*)&pt[tn * 252];
        for (int i = 0; i < 63; ++i) {
            float4 u = pa[i], v = pb[i];
            acc += u.x * v.x + u.y * v.y + u.z * v.z + u.w * v.w;
        }
    }
    if (t < 152) res2[((size_t)b * 8 + cx) * 152 + t] = acc;
}

extern "C" __global__ __launch_bounds__(512, 1)
void mega(const float* __restrict__ x, const float* __restrict__ nl,
          const float* __restrict__ tgt, const float* __restrict__ W,
          const float* __restrict__ bias, const float* __restrict__ nsamp,
          float* __restrict__ xp, const int* __restrict__ tsum,
          float* __restrict__ out, float* __restrict__ res2,
          int* __restrict__ cnt) {
    __shared__ float smem[4800];       // 19.2 KB union (xpred 2176 / ipf 512 / loss 4796)
    const int bid = blockIdx.x;
    const int t = threadIdx.x;
    if (bid < 256) {
        xpred_path(x, nsamp, W, bias, xp, cnt, smem, bid, t);
    } else if (bid < 256 + NB) {
        ipf_path(xp, tsum, out, cnt, smem, bid - 256, t);
    } else {
        const int q = bid - (256 + NB);   // 0..511 -> 8 chunks x 64 b
        loss_path(x, nl, tgt, W, bias, res2, smem, q & 7, q >> 3, t);
    }
}

// K2b: combine the 8 d-chunk partials per b and accumulate the loss.
extern "C" __global__ __launch_bounds__(64)
void k2b_combine(const float* __restrict__ res2, float* __restrict__ out) {
    const int b = blockIdx.x, t = threadIdx.x;
    __shared__ float res[152];
    for (int tau = t; tau < 152; tau += 64) {
        float s = 0.f;
        #pragma unroll
        for (int c = 0; c < 8; ++c) s += res2[((size_t)b * 8 + c) * 152 + tau];
        res[tau] = s;
    }
    __syncthreads();
    if (t == 0) {
        float conf = 0.f;
        for (int m = 0; m < NM; ++m) conf += sqrtf(res[m]);
        conf *= (1.f / NM);
        float pd = 0.f;
        for (int m = 0; m < NM; ++m) {
            const int offm = 16 + m * NM - m * (m - 1) / 2;
            const float sqm = res[offm];
            for (int n = m + 1; n < NM; ++n) {
                const int offn = 16 + n * NM - n * (n - 1) / 2;
                const float sqn = res[offn];
                const float inn = res[offm + (n - m)];
                pd += sqrtf(fmaxf(sqm + sqn - 2.f * inn, 1e-6f));
            }
        }
        pd = 2.f * pd / (float)(NM * (NM - 1));
        atomicAdd(out, (conf - 0.5f * pd) * (1.f / NB));
    }
}

// ---------------------------------------------------------------------------
extern "C" void kernel_launch(void* const* d_in, const int* in_sizes, int n_in,
                              void* d_out, int out_size, void* d_ws, size_t ws_size,
                              hipStream_t stream) {
    const float* x     = (const float*)d_in[0];
    const float* tgt   = (const float*)d_in[1];
    const int*   tsum  = (const int*)d_in[2];
    const float* W     = (const float*)d_in[3];
    const float* bias  = (const float*)d_in[4];
    const float* nl    = (const float*)d_in[5];
    const float* nsamp = (const float*)d_in[6];
    float* out = (float*)d_out;

    (void)in_sizes; (void)n_in; (void)out_size; (void)ws_size;

    const size_t XPB  = (size_t)2048 * 2000 * 4;       // 16,384,000 B
    const size_t RESB = (size_t)NB * 8 * 152 * 4;      // 311,296 B
    float* xp   = (float*)d_ws;
    float* res2 = (float*)((char*)d_ws + XPB);
    int*   cnt  = (int*)((char*)d_ws + XPB + RESB);    // 64 ints

    hipMemsetAsync(d_out, 0, sizeof(float), stream);   // loss accumulator
    hipMemsetAsync(cnt, 0, NB * sizeof(int), stream);  // producer counters

    hipLaunchKernelGGL(mega, dim3(256 + NB + 512), dim3(512), 0, stream,
                       x, nl, tgt, W, bias, nsamp, xp, tsum, out, res2, cnt);
    hipLaunchKernelGGL(k2b_combine, dim3(NB), dim3(64), 0, stream, res2, out);
}

// Round 11
// 321.976 us; speedup vs baseline: 1.0872x; 1.0872x over previous
//
#include <hip/hip_runtime.h>
#include <math.h>

// Problem constants (match reference)
#define NB   64     // num_groups (B)
#define NG   32     // group_size (G)
#define ND   2000   // output dim D
#define NM   16     // m_samples
#define NE   16     // noise dim
#define NDIN 256
#define NK   272    // DIN + E

__device__ __forceinline__ float clampf(float v, float lo, float hi) {
    return fminf(fmaxf(v, lo), hi);
}

__device__ __forceinline__ float softplusf(float v) {
    return (v > 20.f) ? v : log1pf(expf(v));
}

// Broadcast lane `lane`'s value wave-uniformly (lives in SGPR).
__device__ __forceinline__ float readlane_f(float v, int lane) {
    return __int_as_float(__builtin_amdgcn_readlane(__float_as_int(v), lane));
}

// Fully-packed butterfly: reduce v[0..31] across 64 lanes in 32 shuffles.
// Returns the wave total for g = (lane>>1)&31 (dup on lane pairs).
// HW-verified rounds 3-10.
__device__ __forceinline__ float wave_sum32(float v[NG], int lane) {
    {   const bool hi = (lane & 32) != 0;
        #pragma unroll
        for (int k = 0; k < 16; ++k) {
            float s = hi ? v[k] : v[k + 16];
            float r = __shfl_xor(s, 32);
            v[k] = (hi ? v[k + 16] : v[k]) + r;
        }
    }
    {   const bool hi = (lane & 16) != 0;
        #pragma unroll
        for (int k = 0; k < 8; ++k) {
            float s = hi ? v[k] : v[k + 8];
            float r = __shfl_xor(s, 16);
            v[k] = (hi ? v[k + 8] : v[k]) + r;
        }
    }
    {   const bool hi = (lane & 8) != 0;
        #pragma unroll
        for (int k = 0; k < 4; ++k) {
            float s = hi ? v[k] : v[k + 4];
            float r = __shfl_xor(s, 8);
            v[k] = (hi ? v[k + 4] : v[k]) + r;
        }
    }
    {   const bool hi = (lane & 4) != 0;
        #pragma unroll
        for (int k = 0; k < 2; ++k) {
            float s = hi ? v[k] : v[k + 2];
            float r = __shfl_xor(s, 4);
            v[k] = (hi ? v[k + 2] : v[k]) + r;
        }
    }
    {   const bool hi = (lane & 2) != 0;
        float s = hi ? v[0] : v[1];
        float r = __shfl_xor(s, 2);
        v[0] = (hi ? v[1] : v[0]) + r;
    }
    v[0] += __shfl_xor(v[0], 1);
    return v[0];
}

// ---------------------------------------------------------------------------
// Mega kernel (round-9 exact): grid 576 x 512 threads, __launch_bounds__(512,1).
//   blocks 0..63   : IPF + final scale + integerization (b = blockIdx.x)
//   blocks 64..575 : loss partials (8 d-chunks x 64 b)
// LB(512,1) => VGPR cap 512; B[] in SGPRs via readlane; y0 register-resident,
// zero spill (round-9 measured: VGPR 84, WRITE 33.7 MB, 182 us).
// Round-10 lesson: in-kernel producer->consumer handoff for xpred LOSES to a
// plain kernel boundary (resident spinners steal issue slots): reverted.
// ---------------------------------------------------------------------------

// ---- IPF path: thread owns d = 4t..4t+3 full-column (all 32 g) ----
__device__ __forceinline__ void ipf_path(
        const float* __restrict__ xp, const int* __restrict__ tsum,
        float* __restrict__ out, float* smem, int b, int t) {
    const int lane = t & 63, w = t >> 6;      // wave 0..7
    const int d0 = t * 4;
    const bool valid = (d0 < ND);             // t < 500
    const int g_own = (lane >> 1) & 31;

    float* wred = smem;                       // [2][8][32] floats, dbuf

    // load y0 = max(x_pred, 0)
    float y0r[4][NG];
    #pragma unroll
    for (int g = 0; g < NG; ++g) {
        float4 v = make_float4(0.f, 0.f, 0.f, 0.f);
        if (valid) v = *(const float4*)(xp + (size_t)(b * NG + g) * ND + d0);
        y0r[0][g] = fmaxf(v.x, 0.f);
        y0r[1][g] = fmaxf(v.y, 0.f);
        y0r[2][g] = fmaxf(v.z, 0.f);
        y0r[3][g] = fmaxf(v.w, 0.f);
    }
    float Cc[4] = {0.f, 0.f, 0.f, 0.f};
    if (valid) {
        const int4 ci = *(const int4*)(tsum + (size_t)b * ND + d0);
        Cc[0] = (float)ci.x; Cc[1] = (float)ci.y; Cc[2] = (float)ci.z; Cc[3] = (float)ci.w;
    }
    float Ac[4] = {1.f, 1.f, 1.f, 1.f};
    float Bown = 1.f;                         // lane-pair's B[g_own]
    float Rown;                               // lane-pair's R[g_own]

    // prologue: row anchors R (buf 0)
    {
        float v[NG];
        #pragma unroll
        for (int g = 0; g < NG; ++g)
            v[g] = y0r[0][g] + y0r[1][g] + y0r[2][g] + y0r[3][g];
        const float tot = wave_sum32(v, lane);
        if ((lane & 1) == 0) wred[w * NG + g_own] = tot;
        __syncthreads();
        float s = 0.f;
        #pragma unroll
        for (int w2 = 0; w2 < 8; ++w2) s += wred[w2 * NG + g_own];
        Rown = s;
    }

    // 60 IPF iterations, ONE barrier each (double-buffered wred)
    for (int q = 1; q <= 60; ++q) {
        // column phase (thread-local; B broadcast via readlane -> SGPRs)
        float s0 = 0.f, s1 = 0.f, s2 = 0.f, s3 = 0.f;
        #pragma unroll
        for (int g = 0; g < NG; ++g) {
            const float bg = readlane_f(Bown, 2 * g);
            s0 += y0r[0][g] * bg; s1 += y0r[1][g] * bg;
            s2 += y0r[2][g] * bg; s3 += y0r[3][g] * bg;
        }
        Ac[0] *= clampf(Cc[0] / fmaxf(Ac[0] * s0, 1e-12f), 0.75f, 1.25f);
        Ac[1] *= clampf(Cc[1] / fmaxf(Ac[1] * s1, 1e-12f), 0.75f, 1.25f);
        Ac[2] *= clampf(Cc[2] / fmaxf(Ac[2] * s2, 1e-12f), 0.75f, 1.25f);
        Ac[3] *= clampf(Cc[3] / fmaxf(Ac[3] * s3, 1e-12f), 0.75f, 1.25f);
        // row phase
        float v[NG];
        #pragma unroll
        for (int g = 0; g < NG; ++g)
            v[g] = y0r[0][g] * Ac[0] + y0r[1][g] * Ac[1]
                 + y0r[2][g] * Ac[2] + y0r[3][g] * Ac[3];
        const float tot = wave_sum32(v, lane);
        const int buf = (q & 1) * (8 * NG);
        if ((lane & 1) == 0) wred[buf + w * NG + g_own] = tot;
        __syncthreads();
        float s = 0.f;
        #pragma unroll
        for (int w2 = 0; w2 < 8; ++w2) s += wred[buf + w2 * NG + g_own];
        Bown *= clampf(Rown / fmaxf(Bown * s, 1e-12f), 0.75f, 1.25f);
    }

    // epilogue: final scale + exact integerization, thread-local per d.
    // Rank-based neg branch (reference-equivalent): no dynamic indexing.
    if (!valid) return;

    unsigned pk[NG];
    #pragma unroll
    for (int g = 0; g < NG; ++g) pk[g] = 0u;

    #pragma unroll
    for (int j = 0; j < 4; ++j) {
        float fr[NG];
        int   yv[NG];
        float s = 0.f;
        #pragma unroll
        for (int g = 0; g < NG; ++g) {
            const float z = y0r[j][g] * Ac[j] * readlane_f(Bown, 2 * g);
            fr[g] = z;
            s += z;
        }
        const float F = Cc[j] / fmaxf(s, 1e-12f);
        int isum = 0;
        #pragma unroll
        for (int g = 0; g < NG; ++g) {
            const float y = fr[g] * F;
            const float fl = floorf(y);
            yv[g] = (int)fl;
            fr[g] = y - fl;
            isum += yv[g];
        }
        const int Ci = (int)Cc[j];
        const int need = Ci - isum;
        const int pos = max(need, 0);
        const int q = pos >> 5;
        const int r = pos & 31;
        #pragma unroll
        for (int g = 0; g < NG; ++g) yv[g] += q;
        #pragma unroll
        for (int g = 0; g < NG; ++g) {       // stable DESCENDING rank on frac
            int rank = 0;
            #pragma unroll
            for (int h = 0; h < NG; ++h) {
                if (h == g) continue;
                rank += (h < g) ? (fr[h] >= fr[g] ? 1 : 0) : (fr[h] > fr[g] ? 1 : 0);
            }
            if (rank < r) yv[g] += 1;
        }
        // negative residual: one-shot ascending rank among yv>0 (== reference)
        int neg = max(-need, 0);
        neg = min(neg, isum);
        if (__builtin_expect(neg > 0, 0)) {
            const int q2 = neg >> 5;
            int removed = 0;
            #pragma unroll
            for (int g = 0; g < NG; ++g) {
                const int yb = yv[g];
                const int yn = max(yb - q2, 0);
                removed += yb - yn;
                yv[g] = yn;
            }
            const int r2 = neg - removed;
            if (r2 > 0) {
                const float INF = __builtin_inff();
                #pragma unroll
                for (int g = 0; g < NG; ++g) {
                    const float fg = (yv[g] > 0) ? fr[g] : INF;
                    int rank = 0;
                    #pragma unroll
                    for (int h = 0; h < NG; ++h) {
                        if (h == g) continue;
                        const float fh = (yv[h] > 0) ? fr[h] : INF;
                        rank += (h < g) ? (fh <= fg ? 1 : 0) : (fh < fg ? 1 : 0);
                    }
                    if (rank < r2) yv[g] = max(yv[g] - 1, 0);
                }
            }
        }
        #pragma unroll
        for (int g = 0; g < NG; ++g)
            pk[g] |= ((unsigned)yv[g]) << (8 * j);   // yv <= C <= 199 < 256
    }
    #pragma unroll
    for (int g = 0; g < NG; ++g) {
        float* op = &out[1 + (size_t)(b * NG + g) * ND + d0];
        op[0] = (float)(pk[g] & 0xffu);
        op[1] = (float)((pk[g] >> 8) & 0xffu);
        op[2] = (float)((pk[g] >> 16) & 0xffu);
        op[3] = (float)((pk[g] >> 24) & 0xffu);
    }
}

// ---- loss-partials path: 512 blocks = 8 d-chunks x 64 b (round-9 exact) ---
__device__ __forceinline__ void loss_path(
        const float* __restrict__ x, const float* __restrict__ nl,
        const float* __restrict__ tgt, const float* __restrict__ W,
        const float* __restrict__ bias, float* __restrict__ res2,
        float* smem, int cx, int b, int t) {
    float* xsl = smem;                 // 256
    float* nsl = smem + 256;           // 256
    float* tgl = smem + 512;           // 252
    float* pt  = smem + 764;           // 16 x 252

    if (t < 256) {
        const float* xb = x + (size_t)b * NG * NDIN;
        float s = 0.f;
        for (int g = 0; g < NG; ++g) s += xb[g * NDIN + t];
        xsl[t] = s;
        const float* nb = nl + (size_t)b * NG * (NM * NE);
        float s2 = 0.f;
        for (int g = 0; g < NG; ++g) s2 += nb[g * (NM * NE) + t];
        nsl[t] = s2;
    }

    int tm = 0, tn = 0;
    if (t >= 16 && t < 152) {
        int p = t - 16;
        for (int m = 0; m < NM; ++m) {
            int c = NM - m;
            if (p < c) { tm = m; tn = m + p; break; }
            p -= c;
        }
    }
    __syncthreads();

    const int d = cx * 250 + t;
    if (t < 250) {
        tgl[t] = tgt[b * ND + d];
        float xw = 0.f;
        #pragma unroll 8
        for (int k = 0; k < NDIN; ++k) xw += xsl[k] * W[(size_t)k * ND + d];
        float we[NE];
        #pragma unroll
        for (int e = 0; e < NE; ++e) we[e] = W[(size_t)(NDIN + e) * ND + d];
        const float base0 = xw + (float)NG * bias[d];
        #pragma unroll
        for (int m = 0; m < NM; ++m) {
            float pm = base0;
            #pragma unroll
            for (int e = 0; e < NE; ++e) pm += nsl[m * NE + e] * we[e];
            pt[m * 252 + t] = pm;
        }
    }
    if (t < 32) {                      // zero-pad cols 250,251
        pt[(t >> 1) * 252 + 250 + (t & 1)] = 0.f;
        if (t < 2) tgl[250 + t] = 0.f;
    }
    __syncthreads();

    float acc = 0.f;
    if (t < 16) {
        const float4* pa  = (const float4*)&pt[t * 252];
        const float4* tga = (const float4*)&tgl[0];
        for (int i = 0; i < 63; ++i) {
            float4 pv = pa[i], tv = tga[i];
            float e0 = pv.x - tv.x, e1 = pv.y - tv.y, e2 = pv.z - tv.z, e3 = pv.w - tv.w;
            acc += e0 * e0 + e1 * e1 + e2 * e2 + e3 * e3;
        }
    } else if (t < 152) {
        const float4* pa = (const float4*)&pt[tm * 252];
        const float4* pb = (const float4*)&pt[tn * 252];
        for (int i = 0; i < 63; ++i) {
            float4 u = pa[i], v = pb[i];
            acc += u.x * v.x + u.y * v.y + u.z * v.z + u.w * v.w;
        }
    }
    if (t < 152) res2[((size_t)b * 8 + cx) * 152 + t] = acc;
}

extern "C" __global__ __launch_bounds__(512, 1)
void mega(const float* __restrict__ x, const float* __restrict__ nl,
          const float* __restrict__ tgt, const float* __restrict__ W,
          const float* __restrict__ bias, const float* __restrict__ xp,
          const int* __restrict__ tsum, float* __restrict__ out,
          float* __restrict__ res2) {
    __shared__ float smem[4800];       // 19.2 KB, union of both paths
    const int bid = blockIdx.x;
    const int t = threadIdx.x;
    if (bid < NB) {
        ipf_path(xp, tsum, out, smem, bid, t);
    } else {
        const int q = bid - NB;        // 0..511 -> 8 chunks x 64 b
        loss_path(x, nl, tgt, W, bias, res2, smem, q & 7, q >> 3, t);
    }
}

// K2b: combine the 8 d-chunk partials per b and accumulate the loss.
extern "C" __global__ __launch_bounds__(64)
void k2b_combine(const float* __restrict__ res2, float* __restrict__ out) {
    const int b = blockIdx.x, t = threadIdx.x;
    __shared__ float res[152];
    for (int tau = t; tau < 152; tau += 64) {
        float s = 0.f;
        #pragma unroll
        for (int c = 0; c < 8; ++c) s += res2[((size_t)b * 8 + c) * 152 + tau];
        res[tau] = s;
    }
    __syncthreads();
    if (t == 0) {
        float conf = 0.f;
        for (int m = 0; m < NM; ++m) conf += sqrtf(res[m]);
        conf *= (1.f / NM);
        float pd = 0.f;
        for (int m = 0; m < NM; ++m) {
            const int offm = 16 + m * NM - m * (m - 1) / 2;
            const float sqm = res[offm];
            for (int n = m + 1; n < NM; ++n) {
                const int offn = 16 + n * NM - n * (n - 1) / 2;
                const float sqn = res[offn];
                const float inn = res[offm + (n - m)];
                pd += sqrtf(fmaxf(sqm + sqn - 2.f * inn, 1e-6f));
            }
        }
        pd = 2.f * pd / (float)(NM * (NM - 1));
        atomicAdd(out, (conf - 0.5f * pd) * (1.f / NB));
    }
}

// ---------------------------------------------------------------------------
// K3: x_pred = softplus(concat(x, noise_sample) @ W + bias) -> ws.
// Grid (4, 256), 256 threads; thread owns 2 d x 8 rows.  SOFTWARE-PIPELINED:
// W registers double-buffered (load k+4's tiles before consuming k's) so the
// ~300-cycle L2 latency hides behind the 128-FMA body; 1024 blocks = 4
// blocks/CU = 16 waves/CU for TLP on top.  (Rounds 5-9: this kernel was
// stuck at ~120-135 us — 8x its 15 us issue floor — with a bare
// load->wait->use k-loop at 8 waves/CU, insensitive to vector width.)
// Per-(row,d) accumulation expression unchanged => xp bit-identical.
// ---------------------------------------------------------------------------
extern "C" __global__ __launch_bounds__(256)
void k3_xpred(const float* __restrict__ x, const float* __restrict__ nsamp,
              const float* __restrict__ W, const float* __restrict__ bias,
              float* __restrict__ xp) {
    const int dx = blockIdx.x;     // 0..3
    const int rb = blockIdx.y;     // 0..255
    const int t  = threadIdx.x;
    __shared__ float xr[8][NK];
    #pragma unroll
    for (int r = 0; r < 8; ++r) {
        const int row = rb * 8 + r;
        xr[r][t] = x[(size_t)row * NDIN + t];
        if (t < NE) xr[r][NDIN + t] = nsamp[row * NE + t];
    }
    __syncthreads();
    if (t >= 250) return;          // no barriers below
    const int d = dx * 500 + 2 * t;
    float acc[8][2];
    #pragma unroll
    for (int r = 0; r < 8; ++r) { acc[r][0] = 0.f; acc[r][1] = 0.f; }

    float2 wc[4], wn[4];
    #pragma unroll
    for (int kk = 0; kk < 4; ++kk)
        wc[kk] = *(const float2*)&W[(size_t)kk * ND + d];

    for (int k = 0; k < NK; k += 4) {
        // prefetch next k-step's W tiles (in flight across the FMA body)
        if (k + 4 < NK) {
            #pragma unroll
            for (int kk = 0; kk < 4; ++kk)
                wn[kk] = *(const float2*)&W[(size_t)(k + 4 + kk) * ND + d];
        }
        #pragma unroll
        for (int r = 0; r < 8; ++r) {
            const float4 xv = *(const float4*)&xr[r][k];
            acc[r][0] += xv.x * wc[0].x + xv.y * wc[1].x + xv.z * wc[2].x + xv.w * wc[3].x;
            acc[r][1] += xv.x * wc[0].y + xv.y * wc[1].y + xv.z * wc[2].y + xv.w * wc[3].y;
        }
        #pragma unroll
        for (int kk = 0; kk < 4; ++kk) wc[kk] = wn[kk];
    }
    const float2 bv = *(const float2*)&bias[d];
    #pragma unroll
    for (int r = 0; r < 8; ++r) {
        float2 o;
        o.x = softplusf(acc[r][0] + bv.x);
        o.y = softplusf(acc[r][1] + bv.y);
        *(float2*)&xp[(size_t)(rb * 8 + r) * ND + d] = o;
    }
}

// ---------------------------------------------------------------------------
extern "C" void kernel_launch(void* const* d_in, const int* in_sizes, int n_in,
                              void* d_out, int out_size, void* d_ws, size_t ws_size,
                              hipStream_t stream) {
    const float* x     = (const float*)d_in[0];
    const float* tgt   = (const float*)d_in[1];
    const int*   tsum  = (const int*)d_in[2];
    const float* W     = (const float*)d_in[3];
    const float* bias  = (const float*)d_in[4];
    const float* nl    = (const float*)d_in[5];
    const float* nsamp = (const float*)d_in[6];
    float* out = (float*)d_out;
    float* xp  = (float*)d_ws;                         // 2048*2000 floats

    (void)in_sizes; (void)n_in; (void)out_size; (void)ws_size;

    const size_t XPB = (size_t)2048 * 2000 * 4;        // 16,384,000 B
    float* res2 = (float*)((char*)d_ws + XPB);         // 64*8*152 floats

    hipMemsetAsync(d_out, 0, sizeof(float), stream);   // loss accumulator

    hipLaunchKernelGGL(k3_xpred, dim3(4, 256), dim3(256), 0, stream,
                       x, nsamp, W, bias, xp);
    hipLaunchKernelGGL(mega, dim3(NB + 512), dim3(512), 0, stream,
                       x, nl, tgt, W, bias, xp, tsum, out, res2);
    hipLaunchKernelGGL(k2b_combine, dim3(NB), dim3(64), 0, stream, res2, out);
}